// Round 1
// baseline (858.551 us; speedup 1.0000x reference)
//
#include <hip/hip_runtime.h>
#include <math.h>

#define H_ 1024
#define S_ 512
#define B_ 64
#define V_ 50257

typedef unsigned short u16;
typedef __bf16 bf16x8 __attribute__((ext_vector_type(8)));
typedef u16 us8 __attribute__((ext_vector_type(8)));
typedef float f32x4 __attribute__((ext_vector_type(4)));

__device__ __forceinline__ u16 f2bf(float f) {
  union { float f; unsigned u; } v; v.f = f;
  unsigned u = v.u;
  u += 0x7fffu + ((u >> 16) & 1u);   // RNE
  return (u16)(u >> 16);
}
__device__ __forceinline__ float bf2f(u16 s) {
  union { unsigned u; float f; } v; v.u = ((unsigned)s) << 16;
  return v.f;
}
__device__ __forceinline__ void gld16(const void* g, void* l) {
  __builtin_amdgcn_global_load_lds(
      (__attribute__((address_space(1))) void*)g,
      (__attribute__((address_space(3))) void*)l, 16, 0, 0);
}

// ---------------- prep kernels ----------------
__global__ __launch_bounds__(256) void prep_enc(const float* __restrict__ enc,
                                                u16* __restrict__ encbf) {
  size_t i = ((size_t)blockIdx.x * 256 + threadIdx.x) * 8;
  float4 f0 = *(const float4*)(enc + i);
  float4 f1 = *(const float4*)(enc + i + 4);
  us8 u = { f2bf(f0.x), f2bf(f0.y), f2bf(f0.z), f2bf(f0.w),
            f2bf(f1.x), f2bf(f1.y), f2bf(f1.z), f2bf(f1.w) };
  *(us8*)(encbf + i) = u;
}

__global__ __launch_bounds__(256) void prep_w2(const float* __restrict__ attnw,
                                               u16* __restrict__ w2bf) {
  size_t i = ((size_t)blockIdx.x * 256 + threadIdx.x) * 8;
  int n = (int)(i >> 10), k = (int)(i & 1023);
  const float* src = attnw + (size_t)n * 2048 + 1024 + k;
  float4 f0 = *(const float4*)(src);
  float4 f1 = *(const float4*)(src + 4);
  us8 u = { f2bf(f0.x), f2bf(f0.y), f2bf(f0.z), f2bf(f0.w),
            f2bf(f1.x), f2bf(f1.y), f2bf(f1.z), f2bf(f1.w) };
  *(us8*)(w2bf + i) = u;
}

__global__ __launch_bounds__(256) void zero_scores(float* __restrict__ s) {
  int i = (blockIdx.x * 256 + threadIdx.x) * 4;
  *(float4*)(s + i) = make_float4(0.f, 0.f, 0.f, 0.f);
}

// hW1[b][n] = sum_k h[b,k]*attn_w[n,k] + attn_b[n]   (k < 1024 half)
__global__ __launch_bounds__(256) void hw1_kernel(const float* __restrict__ h,
                                                  const float* __restrict__ attnw,
                                                  const float* __restrict__ attnb,
                                                  float* __restrict__ hW1) {
  int n = blockIdx.x * 256 + threadIdx.x;  // gridDim.x = 4
  int b = blockIdx.y;
  const float* w = attnw + (size_t)n * 2048;
  const float* hb = h + (size_t)b * H_;
  float acc = 0.f;
  for (int k = 0; k < H_; k += 4) {
    float4 w4 = *(const float4*)(w + k);
    float4 h4 = *(const float4*)(hb + k);
    acc += w4.x * h4.x + w4.y * h4.y + w4.z * h4.z + w4.w * h4.w;
  }
  hW1[(size_t)b * H_ + n] = acc + attnb[n];
}

// ---------------- fused attention-energy GEMM ----------------
// scores[m] += sum_n v_w[n] * tanh( (enc·W2^T)[m,n] + hW1[b(m),n] )
__global__ __launch_bounds__(256) void attn_gemm(const u16* __restrict__ encbf,
                                                 const u16* __restrict__ w2bf,
                                                 const float* __restrict__ hW1,
                                                 const float* __restrict__ vw,
                                                 float* __restrict__ scores) {
  __shared__ __align__(16) u16 As[128 * 32];
  __shared__ __align__(16) u16 Bs[128 * 32];
  const int t = threadIdx.x;
  const int n0 = blockIdx.x * 128;   // 8 n-tiles
  const int m0 = blockIdx.y * 128;   // 256 m-tiles
  const int lane = t & 63, wid = t >> 6;
  const int wm = (wid >> 1) * 64, wn = (wid & 1) * 64;
  const int col = lane & 15, quad = lane >> 4;

  f32x4 acc[4][4] = {};

  const int srow = t >> 2, scol8 = (t & 3) * 8;
  const u16* ga = encbf + (size_t)(m0 + srow) * H_ + scol8;
  const u16* gb = w2bf + (size_t)(n0 + srow) * H_ + scol8;
  u16* la = &As[t * 8];
  u16* lb = &Bs[t * 8];

  for (int k0 = 0; k0 < H_; k0 += 32) {
    gld16(ga + k0, la);
    gld16(ga + k0 + (size_t)64 * H_, la + 2048);
    gld16(gb + k0, lb);
    gld16(gb + k0 + (size_t)64 * H_, lb + 2048);
    __syncthreads();
    bf16x8 af[4], bfr[4];
#pragma unroll
    for (int i = 0; i < 4; i++)
      af[i] = *(const bf16x8*)&As[(wm + i * 16 + col) * 32 + quad * 8];
#pragma unroll
    for (int j = 0; j < 4; j++)
      bfr[j] = *(const bf16x8*)&Bs[(wn + j * 16 + col) * 32 + quad * 8];
#pragma unroll
    for (int i = 0; i < 4; i++)
#pragma unroll
      for (int j = 0; j < 4; j++)
        acc[i][j] = __builtin_amdgcn_mfma_f32_16x16x32_bf16(af[i], bfr[j], acc[i][j], 0, 0, 0);
    __syncthreads();
  }

  // epilogue: tanh, *v_w, reduce over n within tile, atomic into scores
  const int b = m0 >> 9;   // 128-token tiles never straddle a batch row (512/128=4)
  float sp[4][4] = {{0.f}};
#pragma unroll
  for (int j = 0; j < 4; j++) {
    int n = n0 + wn + j * 16 + col;
    float hw = hW1[(size_t)b * H_ + n];
    float w = vw[n];
#pragma unroll
    for (int i = 0; i < 4; i++)
#pragma unroll
      for (int r = 0; r < 4; r++)
        sp[i][r] += w * tanhf(acc[i][j][r] + hw);
  }
#pragma unroll
  for (int i = 0; i < 4; i++)
#pragma unroll
    for (int r = 0; r < 4; r++) {
      float v = sp[i][r];
      v += __shfl_xor(v, 1, 64);
      v += __shfl_xor(v, 2, 64);
      v += __shfl_xor(v, 4, 64);
      v += __shfl_xor(v, 8, 64);
      if (col == 0) {
        int m = m0 + wm + i * 16 + quad * 4 + r;
        atomicAdd(&scores[m], v);
      }
    }
}

// ---------------- softmax + context ----------------
__global__ __launch_bounds__(256) void softmax_ctx(const float* __restrict__ scores,
                                                   const u16* __restrict__ encbf,
                                                   float* __restrict__ attn_out,
                                                   float* __restrict__ context) {
  __shared__ float sc[512];
  __shared__ float redm[4], reds[4];
  int b = blockIdx.x, t = threadIdx.x;
  int lane = t & 63, wid = t >> 6;
  float s0 = scores[b * 512 + t];
  float s1 = scores[b * 512 + 256 + t];
  float mx = fmaxf(s0, s1);
  for (int off = 32; off; off >>= 1) mx = fmaxf(mx, __shfl_xor(mx, off, 64));
  if (lane == 0) redm[wid] = mx;
  __syncthreads();
  float bm = fmaxf(fmaxf(redm[0], redm[1]), fmaxf(redm[2], redm[3]));
  float e0 = expf(s0 - bm), e1 = expf(s1 - bm);
  float sm = e0 + e1;
  for (int off = 32; off; off >>= 1) sm += __shfl_xor(sm, off, 64);
  if (lane == 0) reds[wid] = sm;
  __syncthreads();
  float inv = 1.f / (reds[0] + reds[1] + reds[2] + reds[3]);
  float a0v = e0 * inv, a1v = e1 * inv;
  sc[t] = a0v; sc[t + 256] = a1v;
  attn_out[b * 512 + t] = a0v;
  attn_out[b * 512 + 256 + t] = a1v;
  __syncthreads();

  // context[b][h] = sum_s attn[s] * enc[b,s,h] ; thread t handles h = 4t..4t+3
  int h0 = t * 4;
  const u16* ep = encbf + (size_t)b * S_ * H_ + h0;
  float p0 = 0.f, p1 = 0.f, p2 = 0.f, p3 = 0.f;     // even-s chain
  float q0 = 0.f, q1 = 0.f, q2 = 0.f, q3 = 0.f;     // odd-s chain
  for (int s = 0; s < S_; s += 2) {
    ushort4 ua = *(const ushort4*)(ep + (size_t)s * H_);
    ushort4 ub = *(const ushort4*)(ep + (size_t)(s + 1) * H_);
    float wa = sc[s], wb = sc[s + 1];
    p0 += wa * bf2f(ua.x); p1 += wa * bf2f(ua.y); p2 += wa * bf2f(ua.z); p3 += wa * bf2f(ua.w);
    q0 += wb * bf2f(ub.x); q1 += wb * bf2f(ub.y); q2 += wb * bf2f(ub.z); q3 += wb * bf2f(ub.w);
  }
  float4 c4 = make_float4(p0 + q0, p1 + q1, p2 + q2, p3 + q3);
  *(float4*)(context + (size_t)b * H_ + h0) = c4;
}

// ---------------- GRU step ----------------
__global__ __launch_bounds__(256) void gru_kernel(const int* __restrict__ ids,
                                                  const float* __restrict__ hprev,
                                                  const float* __restrict__ emb,
                                                  const float* __restrict__ ctx,
                                                  const float* __restrict__ wih,
                                                  const float* __restrict__ whh,
                                                  const float* __restrict__ bih,
                                                  const float* __restrict__ bhh,
                                                  float* __restrict__ hnew_out,
                                                  u16* __restrict__ hnew_bf) {
  int t = threadIdx.x;
  int b = t & 63, hl = t >> 6;
  int h = blockIdx.x * 4 + hl;
  const float* er = emb + (size_t)ids[b] * H_;
  const float* cr = ctx + (size_t)b * H_;
  const float* hr = hprev + (size_t)b * H_;
  const float* wr = wih + (size_t)h * 2048;
  const float* wz = wih + (size_t)(H_ + h) * 2048;
  const float* wn = wih + (size_t)(2 * H_ + h) * 2048;
  const float* vr = whh + (size_t)h * H_;
  const float* vz = whh + (size_t)(H_ + h) * H_;
  const float* vn = whh + (size_t)(2 * H_ + h) * H_;
  float gr = 0.f, gz = 0.f, gn = 0.f, hrr = 0.f, hzz = 0.f, hnn = 0.f;
  for (int k = 0; k < H_; k += 4) {
    float4 e = *(const float4*)(er + k);
    float4 c = *(const float4*)(cr + k);
    float4 hp = *(const float4*)(hr + k);
    float4 wr0 = *(const float4*)(wr + k), wr1 = *(const float4*)(wr + H_ + k);
    float4 wz0 = *(const float4*)(wz + k), wz1 = *(const float4*)(wz + H_ + k);
    float4 wn0 = *(const float4*)(wn + k), wn1 = *(const float4*)(wn + H_ + k);
    float4 vr0 = *(const float4*)(vr + k);
    float4 vz0 = *(const float4*)(vz + k);
    float4 vn0 = *(const float4*)(vn + k);
    gr += e.x * wr0.x + e.y * wr0.y + e.z * wr0.z + e.w * wr0.w
        + c.x * wr1.x + c.y * wr1.y + c.z * wr1.z + c.w * wr1.w;
    gz += e.x * wz0.x + e.y * wz0.y + e.z * wz0.z + e.w * wz0.w
        + c.x * wz1.x + c.y * wz1.y + c.z * wz1.z + c.w * wz1.w;
    gn += e.x * wn0.x + e.y * wn0.y + e.z * wn0.z + e.w * wn0.w
        + c.x * wn1.x + c.y * wn1.y + c.z * wn1.z + c.w * wn1.w;
    hrr += hp.x * vr0.x + hp.y * vr0.y + hp.z * vr0.z + hp.w * vr0.w;
    hzz += hp.x * vz0.x + hp.y * vz0.y + hp.z * vz0.z + hp.w * vz0.w;
    hnn += hp.x * vn0.x + hp.y * vn0.y + hp.z * vn0.z + hp.w * vn0.w;
  }
  float rg = 1.f / (1.f + expf(-(gr + bih[h] + hrr + bhh[h])));
  float zg = 1.f / (1.f + expf(-(gz + bih[H_ + h] + hzz + bhh[H_ + h])));
  float ng = tanhf(gn + bih[2 * H_ + h] + rg * (hnn + bhh[2 * H_ + h]));
  float hp_h = hprev[(size_t)b * H_ + h];
  float out = (1.f - zg) * ng + zg * hp_h;
  hnew_out[(size_t)b * H_ + h] = out;
  hnew_bf[(size_t)b * H_ + h] = f2bf(out);
}

// ---------------- prediction GEMM: pred[64,V] = h_new @ out_w^T + out_b ----------------
__global__ __launch_bounds__(256) void pred_gemm(const u16* __restrict__ hnbf,
                                                 const float* __restrict__ outw,
                                                 const float* __restrict__ outb,
                                                 float* __restrict__ pred) {
  __shared__ __align__(16) u16 As[64 * 32];
  __shared__ __align__(16) u16 Bs[128 * 32];
  const int t = threadIdx.x;
  const int n0 = blockIdx.x * 128;
  const int lane = t & 63, wid = t >> 6;
  const int col = lane & 15, quad = lane >> 4;
  f32x4 acc[4][2] = {};

  const int arow = t >> 2, acol = (t & 3) * 8;
  const int brow = t >> 1, bcol = (t & 1) * 16;
  int gbrow = n0 + brow;
  if (gbrow >= V_) gbrow = V_ - 1;
  const float* gB = outw + (size_t)gbrow * H_ + bcol;
  const u16* gA = hnbf + (size_t)arow * H_ + acol;

  for (int k0 = 0; k0 < H_; k0 += 32) {
    gld16(gA + k0, &As[t * 8]);
    float4 f0 = *(const float4*)(gB + k0);
    float4 f1 = *(const float4*)(gB + k0 + 4);
    float4 f2 = *(const float4*)(gB + k0 + 8);
    float4 f3 = *(const float4*)(gB + k0 + 12);
    us8 u0 = { f2bf(f0.x), f2bf(f0.y), f2bf(f0.z), f2bf(f0.w),
               f2bf(f1.x), f2bf(f1.y), f2bf(f1.z), f2bf(f1.w) };
    us8 u1 = { f2bf(f2.x), f2bf(f2.y), f2bf(f2.z), f2bf(f2.w),
               f2bf(f3.x), f2bf(f3.y), f2bf(f3.z), f2bf(f3.w) };
    *(us8*)&Bs[brow * 32 + bcol] = u0;
    *(us8*)&Bs[brow * 32 + bcol + 8] = u1;
    __syncthreads();
    bf16x8 af[4], bfr[2];
#pragma unroll
    for (int i = 0; i < 4; i++)
      af[i] = *(const bf16x8*)&As[(i * 16 + col) * 32 + quad * 8];
#pragma unroll
    for (int j = 0; j < 2; j++)
      bfr[j] = *(const bf16x8*)&Bs[(wid * 32 + j * 16 + col) * 32 + quad * 8];
#pragma unroll
    for (int i = 0; i < 4; i++)
#pragma unroll
      for (int j = 0; j < 2; j++)
        acc[i][j] = __builtin_amdgcn_mfma_f32_16x16x32_bf16(af[i], bfr[j], acc[i][j], 0, 0, 0);
    __syncthreads();
  }
#pragma unroll
  for (int j = 0; j < 2; j++) {
    int vg = n0 + wid * 32 + j * 16 + col;
    if (vg < V_) {
      float bb = outb[vg];
#pragma unroll
      for (int i = 0; i < 4; i++)
#pragma unroll
        for (int r = 0; r < 4; r++) {
          int m = i * 16 + quad * 4 + r;
          pred[(size_t)m * V_ + vg] = acc[i][j][r] + bb;
        }
    }
  }
}

extern "C" void kernel_launch(void* const* d_in, const int* in_sizes, int n_in,
                              void* d_out, int out_size, void* d_ws, size_t ws_size,
                              hipStream_t stream) {
  const int* input_ids = (const int*)d_in[0];
  const float* hidden = (const float*)d_in[1];
  const float* enc = (const float*)d_in[2];
  const float* emb = (const float*)d_in[3];
  const float* attn_w = (const float*)d_in[4];
  const float* attn_b = (const float*)d_in[5];
  const float* v_w = (const float*)d_in[6];
  const float* w_ih = (const float*)d_in[7];
  const float* w_hh = (const float*)d_in[8];
  const float* b_ih = (const float*)d_in[9];
  const float* b_hh = (const float*)d_in[10];
  const float* out_w = (const float*)d_in[11];
  const float* out_b = (const float*)d_in[12];

  float* pred = (float*)d_out;
  float* hnew_out = pred + (size_t)B_ * V_;
  float* attn_out = hnew_out + (size_t)B_ * H_;

  char* ws = (char*)d_ws;
  u16* encbf = (u16*)ws;                         // 67,108,864 B
  u16* w2bf = (u16*)(ws + 67108864);             //  2,097,152 B
  float* hW1 = (float*)(ws + 69206016);          //    262,144 B
  float* scores = (float*)(ws + 69468160);       //    131,072 B
  float* context = (float*)(ws + 69599232);      //    262,144 B
  u16* hnbf = (u16*)(ws + 69861376);             //    131,072 B

  prep_enc<<<16384, 256, 0, stream>>>(enc, encbf);
  prep_w2<<<512, 256, 0, stream>>>(attn_w, w2bf);
  zero_scores<<<32, 256, 0, stream>>>(scores);
  hw1_kernel<<<dim3(4, 64), 256, 0, stream>>>(hidden, attn_w, attn_b, hW1);
  attn_gemm<<<dim3(8, 256), 256, 0, stream>>>(encbf, w2bf, hW1, v_w, scores);
  softmax_ctx<<<64, 256, 0, stream>>>(scores, encbf, attn_out, context);
  gru_kernel<<<256, 256, 0, stream>>>(input_ids, hidden, emb, context,
                                      w_ih, w_hh, b_ih, b_hh, hnew_out, hnbf);
  pred_gemm<<<((V_ + 127) / 128), 256, 0, stream>>>(hnbf, out_w, out_b, pred);
}

// Round 2
// 705.114 us; speedup vs baseline: 1.2176x; 1.2176x over previous
//
#include <hip/hip_runtime.h>
#include <math.h>

#define H_ 1024
#define S_ 512
#define B_ 64
#define V_ 50257

typedef unsigned short u16;
typedef __bf16 bf16x8 __attribute__((ext_vector_type(8)));
typedef u16 us8 __attribute__((ext_vector_type(8)));
typedef float f32x4 __attribute__((ext_vector_type(4)));

__device__ __forceinline__ u16 f2bf(float f) {
  union { float f; unsigned u; } v; v.f = f;
  unsigned u = v.u;
  u += 0x7fffu + ((u >> 16) & 1u);   // RNE
  return (u16)(u >> 16);
}
__device__ __forceinline__ float bf2f(u16 s) {
  union { unsigned u; float f; } v; v.u = ((unsigned)s) << 16;
  return v.f;
}
__device__ __forceinline__ void gld16(const void* g, void* l) {
  __builtin_amdgcn_global_load_lds(
      (__attribute__((address_space(1))) void*)g,
      (__attribute__((address_space(3))) void*)l, 16, 0, 0);
}

// ---------------- prep kernels ----------------
__global__ __launch_bounds__(256) void prep_enc(const float* __restrict__ enc,
                                                u16* __restrict__ encbf) {
  size_t i = ((size_t)blockIdx.x * 256 + threadIdx.x) * 8;
  float4 f0 = *(const float4*)(enc + i);
  float4 f1 = *(const float4*)(enc + i + 4);
  us8 u = { f2bf(f0.x), f2bf(f0.y), f2bf(f0.z), f2bf(f0.w),
            f2bf(f1.x), f2bf(f1.y), f2bf(f1.z), f2bf(f1.w) };
  *(us8*)(encbf + i) = u;
}

__global__ __launch_bounds__(256) void prep_w2(const float* __restrict__ attnw,
                                               u16* __restrict__ w2bf) {
  size_t i = ((size_t)blockIdx.x * 256 + threadIdx.x) * 8;
  int n = (int)(i >> 10), k = (int)(i & 1023);
  const float* src = attnw + (size_t)n * 2048 + 1024 + k;
  float4 f0 = *(const float4*)(src);
  float4 f1 = *(const float4*)(src + 4);
  us8 u = { f2bf(f0.x), f2bf(f0.y), f2bf(f0.z), f2bf(f0.w),
            f2bf(f1.x), f2bf(f1.y), f2bf(f1.z), f2bf(f1.w) };
  *(us8*)(w2bf + i) = u;
}

// zero scores + hW1 + gi + gh (contiguous region, 491520 floats)
__global__ __launch_bounds__(256) void zero_all(float* __restrict__ s) {
  size_t i = ((size_t)blockIdx.x * 256 + threadIdx.x) * 4;
  *(float4*)(s + i) = make_float4(0.f, 0.f, 0.f, 0.f);
}

// xh[b, 0:1024] = bf16(emb[ids[b]]); xh[b, 2048:3072] = bf16(hidden[b])
__global__ __launch_bounds__(256) void prep_xh(const int* __restrict__ ids,
                                               const float* __restrict__ emb,
                                               const float* __restrict__ hidden,
                                               u16* __restrict__ xh) {
  int b = blockIdx.x, t = threadIdx.x;
  int idx = t * 4;
  const float* er = emb + (size_t)ids[b] * H_;
  const float* hr = hidden + (size_t)b * H_;
  float4 e = *(const float4*)(er + idx);
  float4 h = *(const float4*)(hr + idx);
  ushort4 ue = { f2bf(e.x), f2bf(e.y), f2bf(e.z), f2bf(e.w) };
  ushort4 uh = { f2bf(h.x), f2bf(h.y), f2bf(h.z), f2bf(h.w) };
  *(ushort4*)(xh + (size_t)b * 3072 + idx) = ue;
  *(ushort4*)(xh + (size_t)b * 3072 + 2048 + idx) = uh;
}

// ---------------- generic M=64 MFMA GEMM with split-K ----------------
// out[m, n0+*] (+)= A[m, kbase:kbase+kchunk] (bf16) @ B[n, kbase:...]^T (fp32)
// bias[n] added only by the blockIdx.y==0 block.
__global__ __launch_bounds__(256) void mfma_m64(const u16* __restrict__ A, int lda,
                                                const float* __restrict__ B, int ldb,
                                                int kchunk, const float* __restrict__ bias,
                                                float* __restrict__ out, int ldout) {
  __shared__ __align__(16) u16 As[64 * 32];
  __shared__ __align__(16) u16 Bs[128 * 32];
  const int t = threadIdx.x;
  const int n0 = blockIdx.x * 128;
  const int kbase = blockIdx.y * kchunk;
  const int lane = t & 63, wid = t >> 6;
  const int col = lane & 15, quad = lane >> 4;
  f32x4 acc[4][2] = {};

  const int arow = t >> 2, acol = (t & 3) * 8;
  const int brow = t >> 1, bcol = (t & 1) * 16;
  const float* gB = B + (size_t)(n0 + brow) * ldb + kbase + bcol;
  const u16* gA = A + (size_t)arow * lda + kbase + acol;

  for (int k0 = 0; k0 < kchunk; k0 += 32) {
    gld16(gA + k0, &As[t * 8]);
    float4 f0 = *(const float4*)(gB + k0);
    float4 f1 = *(const float4*)(gB + k0 + 4);
    float4 f2 = *(const float4*)(gB + k0 + 8);
    float4 f3 = *(const float4*)(gB + k0 + 12);
    us8 u0 = { f2bf(f0.x), f2bf(f0.y), f2bf(f0.z), f2bf(f0.w),
               f2bf(f1.x), f2bf(f1.y), f2bf(f1.z), f2bf(f1.w) };
    us8 u1 = { f2bf(f2.x), f2bf(f2.y), f2bf(f2.z), f2bf(f2.w),
               f2bf(f3.x), f2bf(f3.y), f2bf(f3.z), f2bf(f3.w) };
    *(us8*)&Bs[brow * 32 + bcol] = u0;
    *(us8*)&Bs[brow * 32 + bcol + 8] = u1;
    __syncthreads();
    bf16x8 af[4], bfr[2];
#pragma unroll
    for (int i = 0; i < 4; i++)
      af[i] = *(const bf16x8*)&As[(i * 16 + col) * 32 + quad * 8];
#pragma unroll
    for (int j = 0; j < 2; j++)
      bfr[j] = *(const bf16x8*)&Bs[(wid * 32 + j * 16 + col) * 32 + quad * 8];
#pragma unroll
    for (int i = 0; i < 4; i++)
#pragma unroll
      for (int j = 0; j < 2; j++)
        acc[i][j] = __builtin_amdgcn_mfma_f32_16x16x32_bf16(af[i], bfr[j], acc[i][j], 0, 0, 0);
    __syncthreads();
  }
#pragma unroll
  for (int j = 0; j < 2; j++) {
    int n = n0 + wid * 32 + j * 16 + col;
    float bb = (bias != nullptr && blockIdx.y == 0) ? bias[n] : 0.f;
#pragma unroll
    for (int i = 0; i < 4; i++)
#pragma unroll
      for (int r = 0; r < 4; r++) {
        int m = i * 16 + quad * 4 + r;
        atomicAdd(&out[(size_t)m * ldout + n], acc[i][j][r] + bb);
      }
  }
}

// ---------------- fused attention-energy GEMM ----------------
// scores[m] += sum_n v_w[n] * tanh( (enc·W2^T)[m,n] + hW1[b(m),n] )
__global__ __launch_bounds__(256) void attn_gemm(const u16* __restrict__ encbf,
                                                 const u16* __restrict__ w2bf,
                                                 const float* __restrict__ hW1,
                                                 const float* __restrict__ vw,
                                                 float* __restrict__ scores) {
  __shared__ __align__(16) u16 As[128 * 32];
  __shared__ __align__(16) u16 Bs[128 * 32];
  const int t = threadIdx.x;
  const int n0 = blockIdx.x * 128;   // 8 n-tiles
  const int m0 = blockIdx.y * 128;   // 256 m-tiles
  const int lane = t & 63, wid = t >> 6;
  const int wm = (wid >> 1) * 64, wn = (wid & 1) * 64;
  const int col = lane & 15, quad = lane >> 4;

  f32x4 acc[4][4] = {};

  const int srow = t >> 2, scol8 = (t & 3) * 8;
  const u16* ga = encbf + (size_t)(m0 + srow) * H_ + scol8;
  const u16* gb = w2bf + (size_t)(n0 + srow) * H_ + scol8;
  u16* la = &As[t * 8];
  u16* lb = &Bs[t * 8];

  for (int k0 = 0; k0 < H_; k0 += 32) {
    gld16(ga + k0, la);
    gld16(ga + k0 + (size_t)64 * H_, la + 2048);
    gld16(gb + k0, lb);
    gld16(gb + k0 + (size_t)64 * H_, lb + 2048);
    __syncthreads();
    bf16x8 af[4], bfr[4];
#pragma unroll
    for (int i = 0; i < 4; i++)
      af[i] = *(const bf16x8*)&As[(wm + i * 16 + col) * 32 + quad * 8];
#pragma unroll
    for (int j = 0; j < 4; j++)
      bfr[j] = *(const bf16x8*)&Bs[(wn + j * 16 + col) * 32 + quad * 8];
#pragma unroll
    for (int i = 0; i < 4; i++)
#pragma unroll
      for (int j = 0; j < 4; j++)
        acc[i][j] = __builtin_amdgcn_mfma_f32_16x16x32_bf16(af[i], bfr[j], acc[i][j], 0, 0, 0);
    __syncthreads();
  }

  const int b = m0 >> 9;   // 128-token tiles never straddle a batch row
  float sp[4][4] = {{0.f}};
#pragma unroll
  for (int j = 0; j < 4; j++) {
    int n = n0 + wn + j * 16 + col;
    float hw = hW1[(size_t)b * H_ + n];
    float w = vw[n];
#pragma unroll
    for (int i = 0; i < 4; i++)
#pragma unroll
      for (int r = 0; r < 4; r++)
        sp[i][r] += w * tanhf(acc[i][j][r] + hw);
  }
#pragma unroll
  for (int i = 0; i < 4; i++)
#pragma unroll
    for (int r = 0; r < 4; r++) {
      float v = sp[i][r];
      v += __shfl_xor(v, 1, 64);
      v += __shfl_xor(v, 2, 64);
      v += __shfl_xor(v, 4, 64);
      v += __shfl_xor(v, 8, 64);
      if (col == 0) {
        int m = m0 + wm + i * 16 + quad * 4 + r;
        atomicAdd(&scores[m], v);
      }
    }
}

// ---------------- softmax + context (context -> bf16 into xh col 1024) ----------------
__global__ __launch_bounds__(256) void softmax_ctx(const float* __restrict__ scores,
                                                   const u16* __restrict__ encbf,
                                                   float* __restrict__ attn_out,
                                                   u16* __restrict__ xh) {
  __shared__ float sc[512];
  __shared__ float redm[4], reds[4];
  int b = blockIdx.x, t = threadIdx.x;
  int lane = t & 63, wid = t >> 6;
  float s0 = scores[b * 512 + t];
  float s1 = scores[b * 512 + 256 + t];
  float mx = fmaxf(s0, s1);
  for (int off = 32; off; off >>= 1) mx = fmaxf(mx, __shfl_xor(mx, off, 64));
  if (lane == 0) redm[wid] = mx;
  __syncthreads();
  float bm = fmaxf(fmaxf(redm[0], redm[1]), fmaxf(redm[2], redm[3]));
  float e0 = expf(s0 - bm), e1 = expf(s1 - bm);
  float sm = e0 + e1;
  for (int off = 32; off; off >>= 1) sm += __shfl_xor(sm, off, 64);
  if (lane == 0) reds[wid] = sm;
  __syncthreads();
  float inv = 1.f / (reds[0] + reds[1] + reds[2] + reds[3]);
  float a0v = e0 * inv, a1v = e1 * inv;
  sc[t] = a0v; sc[t + 256] = a1v;
  attn_out[b * 512 + t] = a0v;
  attn_out[b * 512 + 256 + t] = a1v;
  __syncthreads();

  int h0 = t * 4;
  const u16* ep = encbf + (size_t)b * S_ * H_ + h0;
  float p0 = 0.f, p1 = 0.f, p2 = 0.f, p3 = 0.f;
  float q0 = 0.f, q1 = 0.f, q2 = 0.f, q3 = 0.f;
  for (int s = 0; s < S_; s += 2) {
    ushort4 ua = *(const ushort4*)(ep + (size_t)s * H_);
    ushort4 ub = *(const ushort4*)(ep + (size_t)(s + 1) * H_);
    float wa = sc[s], wb = sc[s + 1];
    p0 += wa * bf2f(ua.x); p1 += wa * bf2f(ua.y); p2 += wa * bf2f(ua.z); p3 += wa * bf2f(ua.w);
    q0 += wb * bf2f(ub.x); q1 += wb * bf2f(ub.y); q2 += wb * bf2f(ub.z); q3 += wb * bf2f(ub.w);
  }
  ushort4 c = { f2bf(p0 + q0), f2bf(p1 + q1), f2bf(p2 + q2), f2bf(p3 + q3) };
  *(ushort4*)(xh + (size_t)b * 3072 + 1024 + h0) = c;
}

// ---------------- GRU gates (elementwise) ----------------
__global__ __launch_bounds__(256) void gru_gates(const float* __restrict__ gi,
                                                 const float* __restrict__ gh,
                                                 const float* __restrict__ bih,
                                                 const float* __restrict__ bhh,
                                                 const float* __restrict__ hprev,
                                                 float* __restrict__ hnew_out,
                                                 u16* __restrict__ hnew_bf) {
  int idx = blockIdx.x * 256 + threadIdx.x;   // 64*1024
  int b = idx >> 10, h = idx & 1023;
  size_t base = (size_t)b * 3072 + h;
  float ir = gi[base] + bih[h];
  float iz = gi[base + 1024] + bih[H_ + h];
  float in_ = gi[base + 2048] + bih[2 * H_ + h];
  float hr = gh[base] + bhh[h];
  float hz = gh[base + 1024] + bhh[H_ + h];
  float hn = gh[base + 2048] + bhh[2 * H_ + h];
  float rg = 1.f / (1.f + expf(-(ir + hr)));
  float zg = 1.f / (1.f + expf(-(iz + hz)));
  float ng = tanhf(in_ + rg * hn);
  float hp = hprev[(size_t)b * H_ + h];
  float out = (1.f - zg) * ng + zg * hp;
  hnew_out[(size_t)b * H_ + h] = out;
  hnew_bf[(size_t)b * H_ + h] = f2bf(out);
}

// ---------------- prediction GEMM: pred[64,V] = h_new @ out_w^T + out_b ----------------
__global__ __launch_bounds__(256) void pred_gemm(const u16* __restrict__ hnbf,
                                                 const float* __restrict__ outw,
                                                 const float* __restrict__ outb,
                                                 float* __restrict__ pred) {
  __shared__ __align__(16) u16 As[64 * 32];
  __shared__ __align__(16) u16 Bs[128 * 32];
  const int t = threadIdx.x;
  const int n0 = blockIdx.x * 128;
  const int lane = t & 63, wid = t >> 6;
  const int col = lane & 15, quad = lane >> 4;
  f32x4 acc[4][2] = {};

  const int arow = t >> 2, acol = (t & 3) * 8;
  const int brow = t >> 1, bcol = (t & 1) * 16;
  int gbrow = n0 + brow;
  if (gbrow >= V_) gbrow = V_ - 1;
  const float* gB = outw + (size_t)gbrow * H_ + bcol;
  const u16* gA = hnbf + (size_t)arow * H_ + acol;

  for (int k0 = 0; k0 < H_; k0 += 32) {
    gld16(gA + k0, &As[t * 8]);
    float4 f0 = *(const float4*)(gB + k0);
    float4 f1 = *(const float4*)(gB + k0 + 4);
    float4 f2 = *(const float4*)(gB + k0 + 8);
    float4 f3 = *(const float4*)(gB + k0 + 12);
    us8 u0 = { f2bf(f0.x), f2bf(f0.y), f2bf(f0.z), f2bf(f0.w),
               f2bf(f1.x), f2bf(f1.y), f2bf(f1.z), f2bf(f1.w) };
    us8 u1 = { f2bf(f2.x), f2bf(f2.y), f2bf(f2.z), f2bf(f2.w),
               f2bf(f3.x), f2bf(f3.y), f2bf(f3.z), f2bf(f3.w) };
    *(us8*)&Bs[brow * 32 + bcol] = u0;
    *(us8*)&Bs[brow * 32 + bcol + 8] = u1;
    __syncthreads();
    bf16x8 af[4], bfr[2];
#pragma unroll
    for (int i = 0; i < 4; i++)
      af[i] = *(const bf16x8*)&As[(i * 16 + col) * 32 + quad * 8];
#pragma unroll
    for (int j = 0; j < 2; j++)
      bfr[j] = *(const bf16x8*)&Bs[(wid * 32 + j * 16 + col) * 32 + quad * 8];
#pragma unroll
    for (int i = 0; i < 4; i++)
#pragma unroll
      for (int j = 0; j < 2; j++)
        acc[i][j] = __builtin_amdgcn_mfma_f32_16x16x32_bf16(af[i], bfr[j], acc[i][j], 0, 0, 0);
    __syncthreads();
  }
#pragma unroll
  for (int j = 0; j < 2; j++) {
    int vg = n0 + wid * 32 + j * 16 + col;
    if (vg < V_) {
      float bb = outb[vg];
#pragma unroll
      for (int i = 0; i < 4; i++)
#pragma unroll
        for (int r = 0; r < 4; r++) {
          int m = i * 16 + quad * 4 + r;
          pred[(size_t)m * V_ + vg] = acc[i][j][r] + bb;
        }
    }
  }
}

extern "C" void kernel_launch(void* const* d_in, const int* in_sizes, int n_in,
                              void* d_out, int out_size, void* d_ws, size_t ws_size,
                              hipStream_t stream) {
  const int* input_ids = (const int*)d_in[0];
  const float* hidden = (const float*)d_in[1];
  const float* enc = (const float*)d_in[2];
  const float* emb = (const float*)d_in[3];
  const float* attn_w = (const float*)d_in[4];
  const float* attn_b = (const float*)d_in[5];
  const float* v_w = (const float*)d_in[6];
  const float* w_ih = (const float*)d_in[7];
  const float* w_hh = (const float*)d_in[8];
  const float* b_ih = (const float*)d_in[9];
  const float* b_hh = (const float*)d_in[10];
  const float* out_w = (const float*)d_in[11];
  const float* out_b = (const float*)d_in[12];

  float* pred = (float*)d_out;
  float* hnew_out = pred + (size_t)B_ * V_;
  float* attn_out = hnew_out + (size_t)B_ * H_;

  char* ws = (char*)d_ws;
  u16* encbf = (u16*)ws;                          // 67,108,864 B
  u16* w2bf = (u16*)(ws + 67108864);              //  2,097,152 B
  float* scores = (float*)(ws + 69206016);        //    131,072 B  } contiguous
  float* hW1 = (float*)(ws + 69337088);           //    262,144 B  } zero
  float* gi = (float*)(ws + 69599232);            //    786,432 B  } region
  float* gh = (float*)(ws + 70385664);            //    786,432 B  }
  u16* xh = (u16*)(ws + 71172096);                //    393,216 B
  u16* hnbf = (u16*)(ws + 71565312);              //    131,072 B

  prep_enc<<<16384, 256, 0, stream>>>(enc, encbf);
  prep_w2<<<512, 256, 0, stream>>>(attn_w, w2bf);
  zero_all<<<480, 256, 0, stream>>>(scores);      // scores+hW1+gi+gh = 491520 f
  prep_xh<<<64, 256, 0, stream>>>(input_ids, emb, hidden, xh);
  // hW1 = h @ W1^T + attn_b   (N=1024, K=1024, split-K 4x256)
  mfma_m64<<<dim3(8, 4), 256, 0, stream>>>(xh + 2048, 3072, attn_w, 2048, 256,
                                           attn_b, hW1, 1024);
  attn_gemm<<<dim3(8, 256), 256, 0, stream>>>(encbf, w2bf, hW1, v_w, scores);
  softmax_ctx<<<64, 256, 0, stream>>>(scores, encbf, attn_out, xh);
  // gi = [emb|ctx] @ w_ih^T  (N=3072, K=2048, split-K 4x512)
  mfma_m64<<<dim3(24, 4), 256, 0, stream>>>(xh, 3072, w_ih, 2048, 512,
                                            nullptr, gi, 3072);
  // gh = h @ w_hh^T          (N=3072, K=1024, split-K 4x256)
  mfma_m64<<<dim3(24, 4), 256, 0, stream>>>(xh + 2048, 3072, w_hh, 1024, 256,
                                            nullptr, gh, 3072);
  gru_gates<<<256, 256, 0, stream>>>(gi, gh, b_ih, b_hh, hidden, hnew_out, hnbf);
  pred_gemm<<<((V_ + 127) / 128), 256, 0, stream>>>(hnbf, out_w, out_b, pred);
}

// Round 3
// 668.158 us; speedup vs baseline: 1.2850x; 1.0553x over previous
//
#include <hip/hip_runtime.h>
#include <math.h>

#define H_ 1024
#define S_ 512
#define B_ 64
#define V_ 50257

typedef unsigned short u16;
typedef __bf16 bf16x8 __attribute__((ext_vector_type(8)));
typedef u16 us8 __attribute__((ext_vector_type(8)));
typedef float f32x4 __attribute__((ext_vector_type(4)));

__device__ __forceinline__ u16 f2bf(float f) {
  union { float f; unsigned u; } v; v.f = f;
  unsigned u = v.u;
  u += 0x7fffu + ((u >> 16) & 1u);   // RNE
  return (u16)(u >> 16);
}
__device__ __forceinline__ float bf2f(u16 s) {
  union { unsigned u; float f; } v; v.u = ((unsigned)s) << 16;
  return v.f;
}
__device__ __forceinline__ void gld16(const void* g, void* l) {
  __builtin_amdgcn_global_load_lds(
      (__attribute__((address_space(1))) void*)g,
      (__attribute__((address_space(3))) void*)l, 16, 0, 0);
}
// fast tanh: 1 - 2/(e^{2x}+1); v_exp_f32 + v_rcp_f32. x->+inf => 1, x->-inf => -1.
__device__ __forceinline__ float ftanh(float x) {
  float e = __builtin_amdgcn_exp2f(x * 2.8853900817779268f);  // e^{2x}
  return 1.f - 2.f * __builtin_amdgcn_rcpf(e + 1.f);
}

// ---------------- prep kernels ----------------
__global__ __launch_bounds__(256) void prep_enc(const float* __restrict__ enc,
                                                u16* __restrict__ encbf) {
  size_t i = ((size_t)blockIdx.x * 256 + threadIdx.x) * 8;
  float4 f0 = *(const float4*)(enc + i);
  float4 f1 = *(const float4*)(enc + i + 4);
  us8 u = { f2bf(f0.x), f2bf(f0.y), f2bf(f0.z), f2bf(f0.w),
            f2bf(f1.x), f2bf(f1.y), f2bf(f1.z), f2bf(f1.w) };
  *(us8*)(encbf + i) = u;
}

__global__ __launch_bounds__(256) void prep_w2(const float* __restrict__ attnw,
                                               u16* __restrict__ w2bf) {
  size_t i = ((size_t)blockIdx.x * 256 + threadIdx.x) * 8;
  int n = (int)(i >> 10), k = (int)(i & 1023);
  const float* src = attnw + (size_t)n * 2048 + 1024 + k;
  float4 f0 = *(const float4*)(src);
  float4 f1 = *(const float4*)(src + 4);
  us8 u = { f2bf(f0.x), f2bf(f0.y), f2bf(f0.z), f2bf(f0.w),
            f2bf(f1.x), f2bf(f1.y), f2bf(f1.z), f2bf(f1.w) };
  *(us8*)(w2bf + i) = u;
}

__global__ __launch_bounds__(256) void zero_all(float* __restrict__ s) {
  size_t i = ((size_t)blockIdx.x * 256 + threadIdx.x) * 4;
  *(float4*)(s + i) = make_float4(0.f, 0.f, 0.f, 0.f);
}

__global__ __launch_bounds__(256) void zero_pred(float* __restrict__ p, int n4) {
  int i = blockIdx.x * 256 + threadIdx.x;
  if (i < n4) *(float4*)(p + (size_t)i * 4) = make_float4(0.f, 0.f, 0.f, 0.f);
}

// xh[b, 0:1024] = bf16(emb[ids[b]]); xh[b, 2048:3072] = bf16(hidden[b])
__global__ __launch_bounds__(256) void prep_xh(const int* __restrict__ ids,
                                               const float* __restrict__ emb,
                                               const float* __restrict__ hidden,
                                               u16* __restrict__ xh) {
  int b = blockIdx.x, t = threadIdx.x;
  int idx = t * 4;
  const float* er = emb + (size_t)ids[b] * H_;
  const float* hr = hidden + (size_t)b * H_;
  float4 e = *(const float4*)(er + idx);
  float4 h = *(const float4*)(hr + idx);
  ushort4 ue = { f2bf(e.x), f2bf(e.y), f2bf(e.z), f2bf(e.w) };
  ushort4 uh = { f2bf(h.x), f2bf(h.y), f2bf(h.z), f2bf(h.w) };
  *(ushort4*)(xh + (size_t)b * 3072 + idx) = ue;
  *(ushort4*)(xh + (size_t)b * 3072 + 2048 + idx) = uh;
}

// ---------------- generic M=64 MFMA GEMM with split-K ----------------
__global__ __launch_bounds__(256) void mfma_m64(const u16* __restrict__ A, int lda,
                                                const float* __restrict__ B, int ldb,
                                                int kchunk, const float* __restrict__ bias,
                                                float* __restrict__ out, int ldout) {
  __shared__ __align__(16) u16 As[64 * 32];
  __shared__ __align__(16) u16 Bs[128 * 32];
  const int t = threadIdx.x;
  const int n0 = blockIdx.x * 128;
  const int kbase = blockIdx.y * kchunk;
  const int lane = t & 63, wid = t >> 6;
  const int col = lane & 15, quad = lane >> 4;
  f32x4 acc[4][2] = {};

  const int arow = t >> 2, acol = (t & 3) * 8;
  const int brow = t >> 1, bcol = (t & 1) * 16;
  const float* gB = B + (size_t)(n0 + brow) * ldb + kbase + bcol;
  const u16* gA = A + (size_t)arow * lda + kbase + acol;

  for (int k0 = 0; k0 < kchunk; k0 += 32) {
    gld16(gA + k0, &As[t * 8]);
    float4 f0 = *(const float4*)(gB + k0);
    float4 f1 = *(const float4*)(gB + k0 + 4);
    float4 f2 = *(const float4*)(gB + k0 + 8);
    float4 f3 = *(const float4*)(gB + k0 + 12);
    us8 u0 = { f2bf(f0.x), f2bf(f0.y), f2bf(f0.z), f2bf(f0.w),
               f2bf(f1.x), f2bf(f1.y), f2bf(f1.z), f2bf(f1.w) };
    us8 u1 = { f2bf(f2.x), f2bf(f2.y), f2bf(f2.z), f2bf(f2.w),
               f2bf(f3.x), f2bf(f3.y), f2bf(f3.z), f2bf(f3.w) };
    *(us8*)&Bs[brow * 32 + bcol] = u0;
    *(us8*)&Bs[brow * 32 + bcol + 8] = u1;
    __syncthreads();
    bf16x8 af[4], bfr[2];
#pragma unroll
    for (int i = 0; i < 4; i++)
      af[i] = *(const bf16x8*)&As[(i * 16 + col) * 32 + quad * 8];
#pragma unroll
    for (int j = 0; j < 2; j++)
      bfr[j] = *(const bf16x8*)&Bs[(wid * 32 + j * 16 + col) * 32 + quad * 8];
#pragma unroll
    for (int i = 0; i < 4; i++)
#pragma unroll
      for (int j = 0; j < 2; j++)
        acc[i][j] = __builtin_amdgcn_mfma_f32_16x16x32_bf16(af[i], bfr[j], acc[i][j], 0, 0, 0);
    __syncthreads();
  }
#pragma unroll
  for (int j = 0; j < 2; j++) {
    int n = n0 + wid * 32 + j * 16 + col;
    float bb = (bias != nullptr && blockIdx.y == 0) ? bias[n] : 0.f;
#pragma unroll
    for (int i = 0; i < 4; i++)
#pragma unroll
      for (int r = 0; r < 4; r++) {
        int m = i * 16 + quad * 4 + r;
        atomicAdd(&out[(size_t)m * ldout + n], acc[i][j][r] + bb);
      }
  }
}

// ---------------- fused attention-energy GEMM v2 ----------------
// block: 128 m-rows x 256 n-cols; wave: 64m x 128n; XOR-swizzled LDS; fast tanh.
__global__ __launch_bounds__(256, 2) void attn_gemm(const u16* __restrict__ encbf,
                                                    const u16* __restrict__ w2bf,
                                                    const float* __restrict__ hW1,
                                                    const float* __restrict__ vw,
                                                    float* __restrict__ scores) {
  __shared__ __align__(16) u16 As[128 * 32];
  __shared__ __align__(16) u16 Bs[256 * 32];
  const int t = threadIdx.x;
  const int n0 = blockIdx.x * 256;   // 4 n-blocks
  const int m0 = blockIdx.y * 128;   // 256 m-blocks
  const int lane = t & 63, wid = t >> 6;
  const int wm = (wid >> 1) * 64, wn = (wid & 1) * 128;
  const int col = lane & 15, quad = lane >> 4;

  f32x4 acc[4][8] = {};

  // staging: slot(row, kb) <- global(row, kb ^ ((row>>1)&3))
  const int srow = t >> 2, kb = t & 3;
  const int kbs = kb ^ ((srow >> 1) & 3);
  const u16* ga = encbf + (size_t)(m0 + srow) * H_ + kbs * 8;
  const u16* gb = w2bf + (size_t)(n0 + srow) * H_ + kbs * 8;
  u16* la = &As[t * 8];
  u16* lb = &Bs[t * 8];

  // fragment-read swizzle: q2 = quad ^ ((row>>1)&3) ; row = 16*j + col => (col>>1)&3
  const int q2 = quad ^ ((col >> 1) & 3);

  for (int k0 = 0; k0 < H_; k0 += 32) {
    gld16(ga + k0, la);
    gld16(ga + k0 + (size_t)64 * H_, la + 2048);
    gld16(gb + k0, lb);
    gld16(gb + k0 + (size_t)64 * H_, lb + 2048);
    gld16(gb + k0 + (size_t)128 * H_, lb + 4096);
    gld16(gb + k0 + (size_t)192 * H_, lb + 6144);
    __syncthreads();
    bf16x8 af[4], bfr[8];
#pragma unroll
    for (int i = 0; i < 4; i++)
      af[i] = *(const bf16x8*)&As[(wm + i * 16 + col) * 32 + q2 * 8];
#pragma unroll
    for (int j = 0; j < 8; j++)
      bfr[j] = *(const bf16x8*)&Bs[(wn + j * 16 + col) * 32 + q2 * 8];
#pragma unroll
    for (int i = 0; i < 4; i++)
#pragma unroll
      for (int j = 0; j < 8; j++)
        acc[i][j] = __builtin_amdgcn_mfma_f32_16x16x32_bf16(af[i], bfr[j], acc[i][j], 0, 0, 0);
    __syncthreads();
  }

  const int b = m0 >> 9;   // 128-row tiles never straddle a batch row
  float sp[4][4] = {{0.f}};
#pragma unroll
  for (int j = 0; j < 8; j++) {
    int n = n0 + wn + j * 16 + col;
    float hw = hW1[(size_t)b * H_ + n];
    float w = vw[n];
#pragma unroll
    for (int i = 0; i < 4; i++)
#pragma unroll
      for (int r = 0; r < 4; r++)
        sp[i][r] += w * ftanh(acc[i][j][r] + hw);
  }
#pragma unroll
  for (int i = 0; i < 4; i++)
#pragma unroll
    for (int r = 0; r < 4; r++) {
      float v = sp[i][r];
      v += __shfl_xor(v, 1, 64);
      v += __shfl_xor(v, 2, 64);
      v += __shfl_xor(v, 4, 64);
      v += __shfl_xor(v, 8, 64);
      if (col == 0) {
        int m = m0 + wm + i * 16 + quad * 4 + r;
        atomicAdd(&scores[m], v);
      }
    }
}

// ---------------- softmax + context v2: grid (64 b, 4 h-slices) ----------------
__global__ __launch_bounds__(256) void softmax_ctx(const float* __restrict__ scores,
                                                   const u16* __restrict__ encbf,
                                                   float* __restrict__ attn_out,
                                                   u16* __restrict__ xh) {
  __shared__ float sc[512];
  __shared__ float redm[4], reds[4];
  __shared__ __align__(16) float red[4][256];
  int b = blockIdx.x, q = blockIdx.y, t = threadIdx.x;
  int lane = t & 63, wid = t >> 6;
  float s0 = scores[b * 512 + t];
  float s1 = scores[b * 512 + 256 + t];
  float mx = fmaxf(s0, s1);
  for (int off = 32; off; off >>= 1) mx = fmaxf(mx, __shfl_xor(mx, off, 64));
  if (lane == 0) redm[wid] = mx;
  __syncthreads();
  float bm = fmaxf(fmaxf(redm[0], redm[1]), fmaxf(redm[2], redm[3]));
  float e0 = expf(s0 - bm), e1 = expf(s1 - bm);
  float sm = e0 + e1;
  for (int off = 32; off; off >>= 1) sm += __shfl_xor(sm, off, 64);
  if (lane == 0) reds[wid] = sm;
  __syncthreads();
  float inv = 1.f / (reds[0] + reds[1] + reds[2] + reds[3]);
  float a0v = e0 * inv, a1v = e1 * inv;
  sc[t] = a0v; sc[t + 256] = a1v;
  if (q == 0) {
    attn_out[b * 512 + t] = a0v;
    attn_out[b * 512 + 256 + t] = a1v;
  }
  __syncthreads();

  // thread t: s-chunk (t>>6)*128, h-cols q*256 + (t&63)*4 .. +3
  int sseg = t >> 6, hlane = t & 63;
  int h0 = q * 256 + hlane * 4;
  const u16* ep = encbf + (size_t)b * S_ * H_ + h0;
  int sbase = sseg * 128;
  float p0 = 0.f, p1 = 0.f, p2 = 0.f, p3 = 0.f;
  float r0 = 0.f, r1 = 0.f, r2 = 0.f, r3 = 0.f;
  for (int s = 0; s < 128; s += 2) {
    ushort4 ua = *(const ushort4*)(ep + (size_t)(sbase + s) * H_);
    ushort4 ub = *(const ushort4*)(ep + (size_t)(sbase + s + 1) * H_);
    float wa = sc[sbase + s], wb = sc[sbase + s + 1];
    p0 += wa * bf2f(ua.x); p1 += wa * bf2f(ua.y); p2 += wa * bf2f(ua.z); p3 += wa * bf2f(ua.w);
    r0 += wb * bf2f(ub.x); r1 += wb * bf2f(ub.y); r2 += wb * bf2f(ub.z); r3 += wb * bf2f(ub.w);
  }
  *(float4*)&red[sseg][hlane * 4] = make_float4(p0 + r0, p1 + r1, p2 + r2, p3 + r3);
  __syncthreads();
  float sum = red[0][t] + red[1][t] + red[2][t] + red[3][t];
  xh[(size_t)b * 3072 + 1024 + q * 256 + t] = f2bf(sum);
}

// ---------------- GRU gates (elementwise) ----------------
__global__ __launch_bounds__(256) void gru_gates(const float* __restrict__ gi,
                                                 const float* __restrict__ gh,
                                                 const float* __restrict__ bih,
                                                 const float* __restrict__ bhh,
                                                 const float* __restrict__ hprev,
                                                 float* __restrict__ hnew_out,
                                                 u16* __restrict__ hnew_bf) {
  int idx = blockIdx.x * 256 + threadIdx.x;
  int b = idx >> 10, h = idx & 1023;
  size_t base = (size_t)b * 3072 + h;
  float ir = gi[base] + bih[h];
  float iz = gi[base + 1024] + bih[H_ + h];
  float in_ = gi[base + 2048] + bih[2 * H_ + h];
  float hr = gh[base] + bhh[h];
  float hz = gh[base + 1024] + bhh[H_ + h];
  float hn = gh[base + 2048] + bhh[2 * H_ + h];
  float rg = 1.f / (1.f + expf(-(ir + hr)));
  float zg = 1.f / (1.f + expf(-(iz + hz)));
  float ng = tanhf(in_ + rg * hn);
  float hp = hprev[(size_t)b * H_ + h];
  float out = (1.f - zg) * ng + zg * hp;
  hnew_out[(size_t)b * H_ + h] = out;
  hnew_bf[(size_t)b * H_ + h] = f2bf(out);
}

// ---------------- prediction GEMM, split-K x2: pred += h_new @ out_w^T (+ out_b) ----------------
__global__ __launch_bounds__(256) void pred_gemm(const u16* __restrict__ hnbf,
                                                 const float* __restrict__ outw,
                                                 const float* __restrict__ outb,
                                                 float* __restrict__ pred) {
  __shared__ __align__(16) u16 As[64 * 32];
  __shared__ __align__(16) u16 Bs[128 * 32];
  const int t = threadIdx.x;
  const int n0 = blockIdx.x * 128;
  const int kbase = blockIdx.y * 512;
  const int lane = t & 63, wid = t >> 6;
  const int col = lane & 15, quad = lane >> 4;
  f32x4 acc[4][2] = {};

  const int arow = t >> 2, acol = (t & 3) * 8;
  const int brow = t >> 1, bcol = (t & 1) * 16;
  int gbrow = n0 + brow;
  if (gbrow >= V_) gbrow = V_ - 1;
  const float* gB = outw + (size_t)gbrow * H_ + kbase + bcol;
  const u16* gA = hnbf + (size_t)arow * H_ + kbase + acol;

  for (int k0 = 0; k0 < 512; k0 += 32) {
    gld16(gA + k0, &As[t * 8]);
    float4 f0 = *(const float4*)(gB + k0);
    float4 f1 = *(const float4*)(gB + k0 + 4);
    float4 f2 = *(const float4*)(gB + k0 + 8);
    float4 f3 = *(const float4*)(gB + k0 + 12);
    us8 u0 = { f2bf(f0.x), f2bf(f0.y), f2bf(f0.z), f2bf(f0.w),
               f2bf(f1.x), f2bf(f1.y), f2bf(f1.z), f2bf(f1.w) };
    us8 u1 = { f2bf(f2.x), f2bf(f2.y), f2bf(f2.z), f2bf(f2.w),
               f2bf(f3.x), f2bf(f3.y), f2bf(f3.z), f2bf(f3.w) };
    *(us8*)&Bs[brow * 32 + bcol] = u0;
    *(us8*)&Bs[brow * 32 + bcol + 8] = u1;
    __syncthreads();
    bf16x8 af[4], bfr[2];
#pragma unroll
    for (int i = 0; i < 4; i++)
      af[i] = *(const bf16x8*)&As[(i * 16 + col) * 32 + quad * 8];
#pragma unroll
    for (int j = 0; j < 2; j++)
      bfr[j] = *(const bf16x8*)&Bs[(wid * 32 + j * 16 + col) * 32 + quad * 8];
#pragma unroll
    for (int i = 0; i < 4; i++)
#pragma unroll
      for (int j = 0; j < 2; j++)
        acc[i][j] = __builtin_amdgcn_mfma_f32_16x16x32_bf16(af[i], bfr[j], acc[i][j], 0, 0, 0);
    __syncthreads();
  }
#pragma unroll
  for (int j = 0; j < 2; j++) {
    int vg = n0 + wid * 32 + j * 16 + col;
    if (vg < V_) {
      float bb = (blockIdx.y == 0) ? outb[vg] : 0.f;
#pragma unroll
      for (int i = 0; i < 4; i++)
#pragma unroll
        for (int r = 0; r < 4; r++) {
          int m = i * 16 + quad * 4 + r;
          atomicAdd(&pred[(size_t)m * V_ + vg], acc[i][j][r] + bb);
        }
    }
  }
}

extern "C" void kernel_launch(void* const* d_in, const int* in_sizes, int n_in,
                              void* d_out, int out_size, void* d_ws, size_t ws_size,
                              hipStream_t stream) {
  const int* input_ids = (const int*)d_in[0];
  const float* hidden = (const float*)d_in[1];
  const float* enc = (const float*)d_in[2];
  const float* emb = (const float*)d_in[3];
  const float* attn_w = (const float*)d_in[4];
  const float* attn_b = (const float*)d_in[5];
  const float* v_w = (const float*)d_in[6];
  const float* w_ih = (const float*)d_in[7];
  const float* w_hh = (const float*)d_in[8];
  const float* b_ih = (const float*)d_in[9];
  const float* b_hh = (const float*)d_in[10];
  const float* out_w = (const float*)d_in[11];
  const float* out_b = (const float*)d_in[12];

  float* pred = (float*)d_out;
  float* hnew_out = pred + (size_t)B_ * V_;
  float* attn_out = hnew_out + (size_t)B_ * H_;

  char* ws = (char*)d_ws;
  u16* encbf = (u16*)ws;                          // 67,108,864 B
  u16* w2bf = (u16*)(ws + 67108864);              //  2,097,152 B
  float* scores = (float*)(ws + 69206016);        //    131,072 B  } contiguous
  float* hW1 = (float*)(ws + 69337088);           //    262,144 B  } zero
  float* gi = (float*)(ws + 69599232);            //    786,432 B  } region
  float* gh = (float*)(ws + 70385664);            //    786,432 B  }
  u16* xh = (u16*)(ws + 71172096);                //    393,216 B
  u16* hnbf = (u16*)(ws + 71565312);              //    131,072 B

  prep_enc<<<16384, 256, 0, stream>>>(enc, encbf);
  prep_w2<<<512, 256, 0, stream>>>(attn_w, w2bf);
  zero_all<<<480, 256, 0, stream>>>(scores);      // scores+hW1+gi+gh = 491520 f
  zero_pred<<<3142, 256, 0, stream>>>(pred, (B_ * V_) / 4);
  prep_xh<<<64, 256, 0, stream>>>(input_ids, emb, hidden, xh);
  // hW1 = h @ W1^T + attn_b   (N=1024, K=1024, split-K 4x256)
  mfma_m64<<<dim3(8, 4), 256, 0, stream>>>(xh + 2048, 3072, attn_w, 2048, 256,
                                           attn_b, hW1, 1024);
  attn_gemm<<<dim3(4, 256), 256, 0, stream>>>(encbf, w2bf, hW1, v_w, scores);
  softmax_ctx<<<dim3(64, 4), 256, 0, stream>>>(scores, encbf, attn_out, xh);
  // gi = [emb|ctx] @ w_ih^T  (N=3072, K=2048, split-K 4x512)
  mfma_m64<<<dim3(24, 4), 256, 0, stream>>>(xh, 3072, w_ih, 2048, 512,
                                            nullptr, gi, 3072);
  // gh = h @ w_hh^T          (N=3072, K=1024, split-K 4x256)
  mfma_m64<<<dim3(24, 4), 256, 0, stream>>>(xh + 2048, 3072, w_hh, 1024, 256,
                                            nullptr, gh, 3072);
  gru_gates<<<256, 256, 0, stream>>>(gi, gh, b_ih, b_hh, hidden, hnew_out, hnbf);
  pred_gemm<<<dim3((V_ + 127) / 128, 2), 256, 0, stream>>>(hnbf, out_w, out_b, pred);
}